// Round 8
// baseline (1084.905 us; speedup 1.0000x reference)
//
#include <hip/hip_runtime.h>
#include <math.h>

typedef unsigned short u16;
typedef unsigned int u32;
typedef __attribute__((ext_vector_type(8))) short short8;   // 8 bf16 (4 VGPRs)
typedef __attribute__((ext_vector_type(4))) float f32x4;

#define DIM 384
#define HID 1536

static __device__ __forceinline__ float bf2f(u32 b){ return __uint_as_float(b << 16); }
static __device__ __forceinline__ u16 f2bf(float f){
  u32 u = __float_as_uint(f);
  u32 r = (u + 0x7fffu + ((u >> 16) & 1u)) >> 16;
  return (u16)r;
}
// tanh-form GELU via sigmoid; |err| ~1e-4 in our operating range
static __device__ __forceinline__ float gelu_fast(float v){
  float u = v * fmaf(0.0713548162726f, v * v, 1.59576912161f);
  float e = exp2f(-1.44269504089f * u);
  return v * __builtin_amdgcn_rcpf(1.0f + e);
}
// async global->LDS, 16B/lane; LDS dest = wave-uniform base + lane*16
static __device__ __forceinline__ void gload_lds16(const u16* g, u16* l){
  __builtin_amdgcn_global_load_lds(
      (__attribute__((address_space(1))) void*)(void*)const_cast<u16*>(g),
      (__attribute__((address_space(3))) void*)(void*)l, 16, 0, 0);
}

// ---------------- LayerNorm: f32 in, bf16 out ------------------------------
__global__ __launch_bounds__(256) void ln_kernel(const float* __restrict__ x,
    const float* __restrict__ sc, const float* __restrict__ bi, u16* __restrict__ y){
  int lane = threadIdx.x & 63;
  int row = blockIdx.x * 4 + (threadIdx.x >> 6);
  const float* xr = x + (size_t)row * DIM;
  float v[6];
  float s = 0.f, sq = 0.f;
#pragma unroll
  for (int i = 0; i < 6; ++i){
    float f = xr[lane + 64*i];
    v[i] = f; s += f; sq += f*f;
  }
#pragma unroll
  for (int o = 1; o < 64; o <<= 1){ s += __shfl_xor(s, o); sq += __shfl_xor(sq, o); }
  float mean = s * (1.0f/DIM);
  float var = sq * (1.0f/DIM) - mean*mean;
  float inv = rsqrtf(var + 1e-5f);
  u16* yr = y + (size_t)row * DIM;
#pragma unroll
  for (int i = 0; i < 6; ++i){
    int c = lane + 64*i;
    yr[c] = f2bf((v[i] - mean) * inv * sc[c] + bi[c]);
  }
}

// ---------------- 3D RoPE, in-place on q (bf16) ----------------------------
__global__ __launch_bounds__(256) void rope_kernel(u16* __restrict__ q,
    const int* __restrict__ Tp, const int* __restrict__ Hp, const int* __restrict__ Wp,
    int Mtok){
  int idx = blockIdx.x * 256 + threadIdx.x;   // one thread per rotated pair
  int tok = idx / 192;                         // 192 pairs per token
  if (tok >= Mtok) return;
  int p = idx - tok * 192;
  int H = *Hp, W = *Wp, T = *Tp;
  int HW = H * W;
  int Ns = T * HW;
  int n = tok % Ns;
  int head = p / 12;
  int pp = p - head * 12;
  int s = pp >> 2, f = pp & 3;
  float pos;
  if (s == 0)      pos = (float)(n / HW);
  else if (s == 1) pos = (float)((n / W) % H);
  else             pos = (float)(n % W);
  const float LOG2_10000 = 13.28771237954945f;
  float inv = exp2f(-0.25f * (float)f * LOG2_10000);
  float ang = pos * inv;
  float sn = sinf(ang), cs = cosf(ang);
  size_t base = (size_t)tok * DIM + head * 24 + s * 8 + 2 * f;
  u32 u = *(u32*)(q + base);
  float x1 = bf2f(u & 0xffffu), x2 = bf2f(u >> 16);
  float y1 = x1 * cs - x2 * sn;
  float y2 = x1 * sn + x2 * cs;
  *(u32*)(q + base) = (u32)f2bf(y1) | ((u32)f2bf(y2) << 16);
}

// -------- weight transpose+convert: f32 in[R][C] -> bf16 out[C][R'] --------
template<int R, int C>
__global__ __launch_bounds__(256) void transpose_kernel(
    const float* __restrict__ s0, const float* __restrict__ s1,
    const float* __restrict__ s2, const float* __restrict__ s3,
    u16* __restrict__ d0, u16* __restrict__ d1, u16* __restrict__ d2, u16* __restrict__ d3,
    int dstStride){
  const float* src = (blockIdx.z == 0) ? s0 : (blockIdx.z == 1) ? s1 : (blockIdx.z == 2) ? s2 : s3;
  u16* dst         = (blockIdx.z == 0) ? d0 : (blockIdx.z == 1) ? d1 : (blockIdx.z == 2) ? d2 : d3;
  __shared__ u16 t[32][33];
  int tx = threadIdx.x & 31, ty = threadIdx.x >> 5;  // 32 x 8
  int r0 = blockIdx.y * 32, c0 = blockIdx.x * 32;
#pragma unroll
  for (int i = 0; i < 4; ++i)
    t[ty + 8*i][tx] = f2bf(src[(size_t)(r0 + ty + 8*i) * C + c0 + tx]);
  __syncthreads();
#pragma unroll
  for (int i = 0; i < 4; ++i)
    dst[(size_t)(c0 + ty + 8*i) * dstStride + r0 + tx] = t[tx][ty + 8*i];
}

// ---------------- sum 3 bias vectors of 384 --------------------------------
__global__ void bias3_kernel(const float* __restrict__ b, float* __restrict__ o){
  int n = threadIdx.x;
  o[n] = b[n] + b[384 + n] + b[768 + n];
}

// ---------------- MFMA GEMM (R7-verified): C = A @ Bt^T --------------------
enum { E_NONE = 0, E_BIAS = 1, E_BIAS_GELU = 2, E_RES_F32 = 3, E_ACC_F32 = 4, E_FINAL = 5 };

template<int BM, int N, int K, int EPI>
__global__ __launch_bounds__(256) void gemm_kernel(
    const u16* __restrict__ A, const u16* __restrict__ Bt,
    void* __restrict__ Cv, const float* __restrict__ bias,
    const float* __restrict__ res, float* __restrict__ accbuf){
  constexpr int BN = 128, BK = 64;
  constexpr int MT = BM / 32, NT = 4;
  constexpr int AIT = BM / 32, BIT = 4;
  __shared__ __align__(16) u16 As[BM * BK];
  __shared__ __align__(16) u16 Bs[BN * BK];
  const int tid = threadIdx.x;
  const int lane = tid & 63;
  const int wv = tid >> 6;
  const int wm = (wv >> 1) * (BM / 2);
  const int wn = (wv & 1) * 64;
  const int quad = lane >> 4;
  const int l16 = lane & 15;
  const int rsw = l16 & 7;
  const size_t m0 = (size_t)blockIdx.x * BM;
  const int n0 = blockIdx.y * BN;
  const int srow = lane >> 3;
  const int scol = ((lane & 7) ^ srow) * 8;

  f32x4 acc[MT][NT];
  const f32x4 zero = {0.f, 0.f, 0.f, 0.f};
#pragma unroll
  for (int mt = 0; mt < MT; ++mt)
#pragma unroll
    for (int nt = 0; nt < NT; ++nt) acc[mt][nt] = zero;

  for (int kt = 0; kt < K; kt += BK){
#pragma unroll
    for (int i = 0; i < AIT; ++i){
      int seg = i * 4 + wv;
      gload_lds16(A + (m0 + (size_t)(seg * 8 + srow)) * K + kt + scol, As + seg * 512);
    }
#pragma unroll
    for (int i = 0; i < BIT; ++i){
      int seg = i * 4 + wv;
      gload_lds16(Bt + (size_t)(n0 + seg * 8 + srow) * K + kt + scol, Bs + seg * 512);
    }
    __syncthreads();
#pragma unroll
    for (int kk = 0; kk < 2; ++kk){
      short8 af[MT], bfr[NT];
#pragma unroll
      for (int mt = 0; mt < MT; ++mt)
        af[mt] = *(const short8*)(As + (wm + mt*16 + l16) * BK + (((kk*4 + quad) ^ rsw) << 3));
#pragma unroll
      for (int nt = 0; nt < NT; ++nt)
        bfr[nt] = *(const short8*)(Bs + (wn + nt*16 + l16) * BK + (((kk*4 + quad) ^ rsw) << 3));
#pragma unroll
      for (int mt = 0; mt < MT; ++mt)
#pragma unroll
        for (int nt = 0; nt < NT; ++nt)
          acc[mt][nt] = __builtin_amdgcn_mfma_f32_16x16x32_bf16(af[mt], bfr[nt], acc[mt][nt], 0, 0, 0);
    }
    __syncthreads();
  }

#pragma unroll
  for (int mt = 0; mt < MT; ++mt){
#pragma unroll
    for (int nt = 0; nt < NT; ++nt){
      int ncol = n0 + wn + nt*16 + l16;
      float bv = (EPI != E_NONE) ? bias[ncol] : 0.f;
      size_t mbase = m0 + wm + mt*16 + quad*4;
#pragma unroll
      for (int r = 0; r < 4; ++r){
        size_t off = (mbase + r) * N + ncol;
        float vv = acc[mt][nt][r];
        if      (EPI == E_NONE)      ((u16*)Cv)[off] = f2bf(vv);
        else if (EPI == E_BIAS)      ((u16*)Cv)[off] = f2bf(vv + bv);
        else if (EPI == E_BIAS_GELU) ((u16*)Cv)[off] = f2bf(gelu_fast(vv + bv));
        else if (EPI == E_RES_F32)   accbuf[off] = vv + bv + res[off];
        else if (EPI == E_ACC_F32)   accbuf[off] += vv + bv;
        else /* E_FINAL */           ((float*)Cv)[off] = accbuf[off] + vv + bv;
      }
    }
  }
}

// ================= Fused MLP: out = epi(gelu(A@W1+b1)@W2 + b2) =============
// A [M][384] bf16; W1T [HIDN][384] bf16 ([n][k]); W2T [384][HIDN] bf16 ([d][n]).
// EPI 0: out bf16 = acc + b2 (titan t1). EPI 1: out f32 = x2 + acc + b2 (cms).
// Block = 64 rows. LDS: Ys 48K (resident y rows, 6 s-blocks of [64][64]),
// Hs 16K (h tile 64x128, 2 s-blocks), Wst 2x32K double-buffered weight chunks
// [128 rows][128 k]. All swizzled (XOR family, R7-verified conflict-free).
// 7 barriers per 128-col chunk, each (except h) overlapped with async prefetch.
template<int HIDN, int EPI>
__global__ __launch_bounds__(256) void fused_mlp_kernel(
    const u16* __restrict__ A, const u16* __restrict__ W1T,
    const float* __restrict__ b1, const u16* __restrict__ W2T,
    const float* __restrict__ b2, void* __restrict__ out,
    const float* __restrict__ x2){
  constexpr int NJ = HIDN / 128;
  __shared__ __align__(16) u16 lds[65536];          // 128 KB
  u16* Ys  = lds;                                    // 24576 u16
  u16* Hs  = lds + 24576;                            // 8192 u16
  u16* Wst = lds + 32768;                            // 2 x 16384 u16

  const int tid  = threadIdx.x;
  const int lane = tid & 63;
  const int wv   = tid >> 6;
  const int mh   = (wv & 1) * 32;    // row half
  const int wc   = wv >> 1;          // col-tile parity
  const int quad = lane >> 4;
  const int l16  = lane & 15;
  const int rsw8 = l16 & 7;
  const size_t m0 = (size_t)blockIdx.x * 64;

  // weight-chunk stager: [128 rows][128 k] from base (row stride S) -> buf
  auto stage16 = [&](const u16* base, int S, u16* buf){
    int rin = lane >> 4;             // row within 4-row segment
    int c   = lane & 15;             // phys chunk
#pragma unroll
    for (int i = 0; i < 8; ++i){
      int seg = i * 4 + wv;
      int row = seg * 4 + rin;
      gload_lds16(base + (size_t)row * S + (((c ^ (row & 15)) << 3)), buf + seg * 512);
    }
  };

  f32x4 acc2[2][12], acc1[2][4];
  const f32x4 zero = {0.f, 0.f, 0.f, 0.f};
#pragma unroll
  for (int mt = 0; mt < 2; ++mt){
#pragma unroll
    for (int t = 0; t < 12; ++t) acc2[mt][t] = zero;
#pragma unroll
    for (int t = 0; t < 4; ++t)  acc1[mt][t] = zero;
  }

  // ---- prologue: stage resident Ys (A rows m0..m0+64) + first W1 chunk ----
  {
    int sr = lane >> 3;              // row within 8-row segment
    int sc = ((lane & 7) ^ sr) * 8;
#pragma unroll
    for (int g = 0; g < 12; ++g){
      int id = g * 4 + wv;           // 0..47
      int s = id >> 3, seg = id & 7;
      gload_lds16(A + (m0 + seg * 8 + sr) * 384 + s * 64 + sc, Ys + s * 4096 + seg * 512);
    }
  }
  stage16(W1T, 384, Wst);
  __syncthreads();

  int pb = 0;
#pragma unroll 1
  for (int j = 0; j < NJ; ++j){
    // -------- phase 1: h_tile = y @ W1chunk, 3 steps of BK=128 ------------
#pragma unroll 1
    for (int u = 0; u < 3; ++u){
      // prefetch next chunk into other buffer
      if (u < 2) stage16(W1T + (size_t)j * 128 * 384 + (u + 1) * 128, 384, Wst + (pb ^ 1) * 16384);
      else       stage16(W2T + (size_t)j * 128, HIDN, Wst + (pb ^ 1) * 16384);  // W2 ds=0
      const u16* Wb = Wst + pb * 16384;
#pragma unroll
      for (int kk = 0; kk < 4; ++kk){
        short8 af[2], bfr[4];
        int s = u * 2 + (kk >> 1);
        int c8 = ((kk & 1) * 4 + quad) ^ rsw8;
#pragma unroll
        for (int mt = 0; mt < 2; ++mt)
          af[mt] = *(const short8*)(Ys + s * 4096 + (mh + mt*16 + l16) * 64 + (c8 << 3));
        int c16 = (kk * 4 + quad) ^ l16;
#pragma unroll
        for (int i = 0; i < 4; ++i)
          bfr[i] = *(const short8*)(Wb + ((2*i + wc) * 16 + l16) * 128 + (c16 << 3));
#pragma unroll
        for (int mt = 0; mt < 2; ++mt)
#pragma unroll
          for (int i = 0; i < 4; ++i)
            acc1[mt][i] = __builtin_amdgcn_mfma_f32_16x16x32_bf16(af[mt], bfr[i], acc1[mt][i], 0, 0, 0);
      }
      __syncthreads();
      pb ^= 1;
    }
    // -------- gelu + write h tile to Hs -----------------------------------
#pragma unroll
    for (int i = 0; i < 4; ++i){
      int nl = (2*i + wc) * 16 + l16;
      float bv = b1[j * 128 + nl];
#pragma unroll
      for (int mt = 0; mt < 2; ++mt){
#pragma unroll
        for (int r = 0; r < 4; ++r){
          int m = mh + mt*16 + quad*4 + r;
          float v = gelu_fast(acc1[mt][i][r] + bv);
          Hs[(nl >> 6) * 4096 + m * 64 + ((((nl >> 3) & 7) ^ (m & 7)) << 3) + (nl & 7)] = f2bf(v);
        }
        acc1[mt][i] = zero;
      }
    }
    __syncthreads();
    // -------- phase 2: acc2 += h_tile @ W2chunk, 3 steps (d-subs) ---------
#pragma unroll 1
    for (int u = 3; u < 6; ++u){
      int ds = u - 3;
      if (u < 5)           stage16(W2T + (size_t)(ds + 1) * 128 * HIDN + (size_t)j * 128, HIDN, Wst + (pb ^ 1) * 16384);
      else if (j + 1 < NJ) stage16(W1T + (size_t)(j + 1) * 128 * 384, 384, Wst + (pb ^ 1) * 16384);
      const u16* Wb = Wst + pb * 16384;
#pragma unroll
      for (int kk = 0; kk < 4; ++kk){
        short8 af[2], bfr[4];
        int kh = kk >> 1;
        int c8 = ((kk & 1) * 4 + quad) ^ rsw8;
#pragma unroll
        for (int mt = 0; mt < 2; ++mt)
          af[mt] = *(const short8*)(Hs + kh * 4096 + (mh + mt*16 + l16) * 64 + (c8 << 3));
        int c16 = (kk * 4 + quad) ^ l16;
#pragma unroll
        for (int i = 0; i < 4; ++i)
          bfr[i] = *(const short8*)(Wb + ((2*i + wc) * 16 + l16) * 128 + (c16 << 3));
#pragma unroll
        for (int mt = 0; mt < 2; ++mt)
#pragma unroll
          for (int i = 0; i < 4; ++i)
            acc2[mt][ds*4 + i] = __builtin_amdgcn_mfma_f32_16x16x32_bf16(af[mt], bfr[i], acc2[mt][ds*4 + i], 0, 0, 0);
      }
      __syncthreads();
      pb ^= 1;
    }
  }

  // -------- epilogue: 64 rows x 384 cols ----------------------------------
#pragma unroll
  for (int mt = 0; mt < 2; ++mt){
#pragma unroll
    for (int t = 0; t < 12; ++t){
      int ds = t >> 2, i = t & 3;
      int d = ds * 128 + (2*i + wc) * 16 + l16;
      float bv = b2[d];
#pragma unroll
      for (int r = 0; r < 4; ++r){
        size_t off = (m0 + mh + mt*16 + quad*4 + r) * 384 + d;
        float v = acc2[mt][t][r] + bv;
        if (EPI == 0) ((u16*)out)[off] = f2bf(v);
        else          ((float*)out)[off] = x2[off] + v;
      }
    }
  }
}

extern "C" void kernel_launch(void* const* d_in, const int* in_sizes, int n_in,
                              void* d_out, int out_size, void* d_ws, size_t ws_size,
                              hipStream_t stream) {
  const int W11 = DIM * HID;   // 589824
  const float* x   = (const float*)d_in[0];
  const float* n1s = (const float*)d_in[1];
  const float* n1b = (const float*)d_in[2];
  const float* n2s = (const float*)d_in[3];
  const float* n2b = (const float*)d_in[4];
  const float* qw  = (const float*)d_in[5];
  const float* tw1 = (const float*)d_in[6] + 4 * W11;  // titan_w1[4]
  const float* tb1 = (const float*)d_in[7] + 4 * HID;  // titan_b1[4]
  const float* tw2 = (const float*)d_in[8] + 4 * W11;  // titan_w2[4]
  const float* tb2 = (const float*)d_in[9] + 4 * DIM;  // titan_b2[4]
  const float* ow  = (const float*)d_in[10];
  const float* ob  = (const float*)d_in[11];
  const float* cw1 = (const float*)d_in[12];
  const float* cb1 = (const float*)d_in[13];            // [3][1536] = flat [4608]
  const float* cw2 = (const float*)d_in[14];
  const float* cb2 = (const float*)d_in[15];
  const int* Tp = (const int*)d_in[16];
  const int* Hp = (const int*)d_in[17];
  const int* Wp = (const int*)d_in[18];
  const int M = in_sizes[0] / DIM;   // 16384 tokens

  // workspace layout (bytes), ~47.8 MB total
  char* ws = (char*)d_ws;
  u16*  y    = (u16*) (ws + 0);          // M x 384 bf16
  float* x2  = (float*)(ws + 12582912);  // M x 384 f32
  u16*  qwT  = (u16*) (ws + 37748736);   // 384 x 384
  u16*  owT  = (u16*) (ws + 38043648);   // 384 x 384
  u16*  w1T  = (u16*) (ws + 38338560);   // 1536 x 384
  u16*  w2T  = (u16*) (ws + 39518208);   // 384 x 1536
  u16*  cw1T = (u16*) (ws + 40697856);   // 4608 x 384 (3 stacked)
  u16*  cw2T = (u16*) (ws + 44236800);   // 384 x 4608 (k-stacked)
  float* cb2s = (float*)(ws + 47775744); // 384 f32
  u16*  qb   = (u16*)d_out;              // bf16 scratch: q -> t1; final f32 out
  if (ws_size < 47777280u) return;

  // 1. weight transposes to [out][in] bf16
  transpose_kernel<384,384><<<dim3(12,12,2),256,0,stream>>>(
      qw, ow, qw, qw, qwT, owT, qwT, qwT, 384);
  transpose_kernel<384,1536><<<dim3(48,12,4),256,0,stream>>>(
      tw1, cw1, cw1 + W11, cw1 + 2*W11, w1T, cw1T, cw1T + W11, cw1T + 2*W11, 384);
  transpose_kernel<1536,384><<<dim3(12,48,1),256,0,stream>>>(
      tw2, tw2, tw2, tw2, w2T, w2T, w2T, w2T, 1536);
  transpose_kernel<1536,384><<<dim3(12,48,3),256,0,stream>>>(
      cw2, cw2 + W11, cw2 + 2*W11, cw2, cw2T, cw2T + 1536, cw2T + 3072, cw2T, 4608);
  bias3_kernel<<<1,384,0,stream>>>(cb2, cb2s);

  // 2. y = LN1(x)
  ln_kernel<<<M/4,256,0,stream>>>(x, n1s, n1b, y);
  // 3. q = y @ q_w   (bf16, into d_out)
  gemm_kernel<64,384,384,E_NONE><<<dim3(M/64,3),256,0,stream>>>(y, qwT, qb, nullptr, nullptr, nullptr);
  // 4. RoPE(q) in-place
  rope_kernel<<<(M*192)/256,256,0,stream>>>(qb, Tp, Hp, Wp, M);
  // 5. t1 = gelu(q @ w1 + b1) @ w2 + b2   (fused, in-place in d_out)
  fused_mlp_kernel<1536,0><<<M/64,256,0,stream>>>(qb, w1T, tb1, w2T, tb2, qb, nullptr);
  // 6. x2 = x + t1 @ out_w + out_b   (f32)
  gemm_kernel<64,384,384,E_RES_F32><<<dim3(M/64,3),256,0,stream>>>(qb, owT, nullptr, ob, x, x2);
  // 7. y2 = LN2(x2)
  ln_kernel<<<M/4,256,0,stream>>>(x2, n2s, n2b, y);
  // 8. out = x2 + sum_i gelu(y2 @ cw1_i + cb1_i) @ cw2_i + cb2_i   (fused, f32)
  fused_mlp_kernel<4608,1><<<M/64,256,0,stream>>>(y, cw1T, cb1, cw2T, cb2s, d_out, x2);
}

// Round 9
// 529.140 us; speedup vs baseline: 2.0503x; 2.0503x over previous
//
#include <hip/hip_runtime.h>
#include <math.h>

typedef unsigned short u16;
typedef unsigned int u32;
typedef __attribute__((ext_vector_type(8))) short short8;   // 8 bf16 (4 VGPRs)
typedef __attribute__((ext_vector_type(4))) float f32x4;

#define DIM 384
#define HID 1536

static __device__ __forceinline__ float bf2f(u32 b){ return __uint_as_float(b << 16); }
static __device__ __forceinline__ u16 f2bf(float f){
  u32 u = __float_as_uint(f);
  u32 r = (u + 0x7fffu + ((u >> 16) & 1u)) >> 16;
  return (u16)r;
}
// tanh-form GELU via sigmoid; |err| ~1e-4 in our operating range
static __device__ __forceinline__ float gelu_fast(float v){
  float u = v * fmaf(0.0713548162726f, v * v, 1.59576912161f);
  float e = exp2f(-1.44269504089f * u);
  return v * __builtin_amdgcn_rcpf(1.0f + e);
}
// async global->LDS, 16B/lane; LDS dest = wave-uniform base + lane*16
static __device__ __forceinline__ void gload_lds16(const u16* g, u16* l){
  __builtin_amdgcn_global_load_lds(
      (__attribute__((address_space(1))) void*)(void*)const_cast<u16*>(g),
      (__attribute__((address_space(3))) void*)(void*)l, 16, 0, 0);
}

// ---------------- LayerNorm: f32 in, bf16 out ------------------------------
__global__ __launch_bounds__(256) void ln_kernel(const float* __restrict__ x,
    const float* __restrict__ sc, const float* __restrict__ bi, u16* __restrict__ y){
  int lane = threadIdx.x & 63;
  int row = blockIdx.x * 4 + (threadIdx.x >> 6);
  const float* xr = x + (size_t)row * DIM;
  float v[6];
  float s = 0.f, sq = 0.f;
#pragma unroll
  for (int i = 0; i < 6; ++i){
    float f = xr[lane + 64*i];
    v[i] = f; s += f; sq += f*f;
  }
#pragma unroll
  for (int o = 1; o < 64; o <<= 1){ s += __shfl_xor(s, o); sq += __shfl_xor(sq, o); }
  float mean = s * (1.0f/DIM);
  float var = sq * (1.0f/DIM) - mean*mean;
  float inv = rsqrtf(var + 1e-5f);
  u16* yr = y + (size_t)row * DIM;
#pragma unroll
  for (int i = 0; i < 6; ++i){
    int c = lane + 64*i;
    yr[c] = f2bf((v[i] - mean) * inv * sc[c] + bi[c]);
  }
}

// ---------------- 3D RoPE, in-place on q (bf16) ----------------------------
__global__ __launch_bounds__(256) void rope_kernel(u16* __restrict__ q,
    const int* __restrict__ Tp, const int* __restrict__ Hp, const int* __restrict__ Wp,
    int Mtok){
  int idx = blockIdx.x * 256 + threadIdx.x;   // one thread per rotated pair
  int tok = idx / 192;                         // 192 pairs per token
  if (tok >= Mtok) return;
  int p = idx - tok * 192;
  int H = *Hp, W = *Wp, T = *Tp;
  int HW = H * W;
  int Ns = T * HW;
  int n = tok % Ns;
  int head = p / 12;
  int pp = p - head * 12;
  int s = pp >> 2, f = pp & 3;
  float pos;
  if (s == 0)      pos = (float)(n / HW);
  else if (s == 1) pos = (float)((n / W) % H);
  else             pos = (float)(n % W);
  const float LOG2_10000 = 13.28771237954945f;
  float inv = exp2f(-0.25f * (float)f * LOG2_10000);
  float ang = pos * inv;
  float sn = sinf(ang), cs = cosf(ang);
  size_t base = (size_t)tok * DIM + head * 24 + s * 8 + 2 * f;
  u32 u = *(u32*)(q + base);
  float x1 = bf2f(u & 0xffffu), x2 = bf2f(u >> 16);
  float y1 = x1 * cs - x2 * sn;
  float y2 = x1 * sn + x2 * cs;
  *(u32*)(q + base) = (u32)f2bf(y1) | ((u32)f2bf(y2) << 16);
}

// -------- weight transpose+convert: f32 in[R][C] -> bf16 out[C][R'] --------
template<int R, int C>
__global__ __launch_bounds__(256) void transpose_kernel(
    const float* __restrict__ s0, const float* __restrict__ s1,
    const float* __restrict__ s2, const float* __restrict__ s3,
    u16* __restrict__ d0, u16* __restrict__ d1, u16* __restrict__ d2, u16* __restrict__ d3,
    int dstStride){
  const float* src = (blockIdx.z == 0) ? s0 : (blockIdx.z == 1) ? s1 : (blockIdx.z == 2) ? s2 : s3;
  u16* dst         = (blockIdx.z == 0) ? d0 : (blockIdx.z == 1) ? d1 : (blockIdx.z == 2) ? d2 : d3;
  __shared__ u16 t[32][33];
  int tx = threadIdx.x & 31, ty = threadIdx.x >> 5;  // 32 x 8
  int r0 = blockIdx.y * 32, c0 = blockIdx.x * 32;
#pragma unroll
  for (int i = 0; i < 4; ++i)
    t[ty + 8*i][tx] = f2bf(src[(size_t)(r0 + ty + 8*i) * C + c0 + tx]);
  __syncthreads();
#pragma unroll
  for (int i = 0; i < 4; ++i)
    dst[(size_t)(c0 + ty + 8*i) * dstStride + r0 + tx] = t[tx][ty + 8*i];
}

// ---------------- sum 3 bias vectors of 384 --------------------------------
__global__ void bias3_kernel(const float* __restrict__ b, float* __restrict__ o){
  int n = threadIdx.x;
  o[n] = b[n] + b[384 + n] + b[768 + n];
}

// ---------------- MFMA GEMM (R7-verified): C = A @ Bt^T --------------------
enum { E_NONE = 0, E_BIAS = 1, E_BIAS_GELU = 2, E_RES_F32 = 3, E_ACC_F32 = 4, E_FINAL = 5 };

template<int BM, int N, int K, int EPI>
__global__ __launch_bounds__(256) void gemm_kernel(
    const u16* __restrict__ A, const u16* __restrict__ Bt,
    void* __restrict__ Cv, const float* __restrict__ bias,
    const float* __restrict__ res, float* __restrict__ accbuf){
  constexpr int BN = 128, BK = 64;
  constexpr int MT = BM / 32, NT = 4;
  constexpr int AIT = BM / 32, BIT = 4;
  __shared__ __align__(16) u16 As[BM * BK];
  __shared__ __align__(16) u16 Bs[BN * BK];
  const int tid = threadIdx.x;
  const int lane = tid & 63;
  const int wv = tid >> 6;
  const int wm = (wv >> 1) * (BM / 2);
  const int wn = (wv & 1) * 64;
  const int quad = lane >> 4;
  const int l16 = lane & 15;
  const int rsw = l16 & 7;
  const size_t m0 = (size_t)blockIdx.x * BM;
  const int n0 = blockIdx.y * BN;
  const int srow = lane >> 3;
  const int scol = ((lane & 7) ^ srow) * 8;

  f32x4 acc[MT][NT];
  const f32x4 zero = {0.f, 0.f, 0.f, 0.f};
#pragma unroll
  for (int mt = 0; mt < MT; ++mt)
#pragma unroll
    for (int nt = 0; nt < NT; ++nt) acc[mt][nt] = zero;

  for (int kt = 0; kt < K; kt += BK){
#pragma unroll
    for (int i = 0; i < AIT; ++i){
      int seg = i * 4 + wv;
      gload_lds16(A + (m0 + (size_t)(seg * 8 + srow)) * K + kt + scol, As + seg * 512);
    }
#pragma unroll
    for (int i = 0; i < BIT; ++i){
      int seg = i * 4 + wv;
      gload_lds16(Bt + (size_t)(n0 + seg * 8 + srow) * K + kt + scol, Bs + seg * 512);
    }
    __syncthreads();
#pragma unroll
    for (int kk = 0; kk < 2; ++kk){
      short8 af[MT], bfr[NT];
#pragma unroll
      for (int mt = 0; mt < MT; ++mt)
        af[mt] = *(const short8*)(As + (wm + mt*16 + l16) * BK + (((kk*4 + quad) ^ rsw) << 3));
#pragma unroll
      for (int nt = 0; nt < NT; ++nt)
        bfr[nt] = *(const short8*)(Bs + (wn + nt*16 + l16) * BK + (((kk*4 + quad) ^ rsw) << 3));
#pragma unroll
      for (int mt = 0; mt < MT; ++mt)
#pragma unroll
        for (int nt = 0; nt < NT; ++nt)
          acc[mt][nt] = __builtin_amdgcn_mfma_f32_16x16x32_bf16(af[mt], bfr[nt], acc[mt][nt], 0, 0, 0);
    }
    __syncthreads();
  }

#pragma unroll
  for (int mt = 0; mt < MT; ++mt){
#pragma unroll
    for (int nt = 0; nt < NT; ++nt){
      int ncol = n0 + wn + nt*16 + l16;
      float bv = (EPI != E_NONE) ? bias[ncol] : 0.f;
      size_t mbase = m0 + wm + mt*16 + quad*4;
#pragma unroll
      for (int r = 0; r < 4; ++r){
        size_t off = (mbase + r) * N + ncol;
        float vv = acc[mt][nt][r];
        if      (EPI == E_NONE)      ((u16*)Cv)[off] = f2bf(vv);
        else if (EPI == E_BIAS)      ((u16*)Cv)[off] = f2bf(vv + bv);
        else if (EPI == E_BIAS_GELU) ((u16*)Cv)[off] = f2bf(gelu_fast(vv + bv));
        else if (EPI == E_RES_F32)   accbuf[off] = vv + bv + res[off];
        else if (EPI == E_ACC_F32)   accbuf[off] += vv + bv;
        else /* E_FINAL */           ((float*)Cv)[off] = accbuf[off] + vv + bv;
      }
    }
  }
}

// ================= Fused MLP: out = epi(gelu(A@W1+b1)@W2 + b2) =============
// Geometry identical to R8 (numerics verified). Fix vs R8: phase loops are
// FULLY UNROLLED so all acc indices are compile-time (R8's runtime `ds` sent
// acc2 to scratch: 930 MB spill traffic), and __launch_bounds__(256,1) lifts
// the VGPR cap (1 block/CU anyway due to 128 KB LDS).
template<int HIDN, int EPI>
__global__ __launch_bounds__(256, 1) void fused_mlp_kernel(
    const u16* __restrict__ A, const u16* __restrict__ W1T,
    const float* __restrict__ b1, const u16* __restrict__ W2T,
    const float* __restrict__ b2, void* __restrict__ out,
    const float* __restrict__ x2){
  constexpr int NJ = HIDN / 128;
  __shared__ __align__(16) u16 lds[65536];          // 128 KB
  u16* Ys  = lds;                                    // 24576 u16
  u16* Hs  = lds + 24576;                            // 8192 u16
  u16* Wst = lds + 32768;                            // 2 x 16384 u16

  const int tid  = threadIdx.x;
  const int lane = tid & 63;
  const int wv   = tid >> 6;
  const int mh   = (wv & 1) * 32;    // row half
  const int wc   = wv >> 1;          // col-tile parity
  const int quad = lane >> 4;
  const int l16  = lane & 15;
  const int rsw8 = l16 & 7;
  const size_t m0 = (size_t)blockIdx.x * 64;

  // weight-chunk stager: [128 rows][128 k] from base (row stride S) -> buf
  auto stage16 = [&](const u16* base, int S, u16* buf){
    int rin = lane >> 4;             // row within 4-row segment
    int c   = lane & 15;             // phys chunk
#pragma unroll
    for (int i = 0; i < 8; ++i){
      int seg = i * 4 + wv;
      int row = seg * 4 + rin;
      gload_lds16(base + (size_t)row * S + (((c ^ (row & 15)) << 3)), buf + seg * 512);
    }
  };

  f32x4 acc2[2][12], acc1[2][4];
  const f32x4 zero = {0.f, 0.f, 0.f, 0.f};
#pragma unroll
  for (int mt = 0; mt < 2; ++mt){
#pragma unroll
    for (int t = 0; t < 12; ++t) acc2[mt][t] = zero;
#pragma unroll
    for (int t = 0; t < 4; ++t)  acc1[mt][t] = zero;
  }

  // ---- prologue: stage resident Ys (A rows m0..m0+64) + first W1 chunk ----
  {
    int sr = lane >> 3;              // row within 8-row segment
    int sc = ((lane & 7) ^ sr) * 8;
#pragma unroll
    for (int g = 0; g < 12; ++g){
      int id = g * 4 + wv;           // 0..47
      int s = id >> 3, seg = id & 7;
      gload_lds16(A + (m0 + seg * 8 + sr) * 384 + s * 64 + sc, Ys + s * 4096 + seg * 512);
    }
  }
  stage16(W1T, 384, Wst);
  __syncthreads();

  int pb = 0;
#pragma unroll 1
  for (int j = 0; j < NJ; ++j){
    // -------- phase 1: h_tile = y @ W1chunk, 3 steps of BK=128 (UNROLLED) --
#pragma unroll
    for (int u = 0; u < 3; ++u){
      if (u < 2) stage16(W1T + (size_t)j * 128 * 384 + (u + 1) * 128, 384, Wst + (pb ^ 1) * 16384);
      else       stage16(W2T + (size_t)j * 128, HIDN, Wst + (pb ^ 1) * 16384);
      const u16* Wb = Wst + pb * 16384;
#pragma unroll
      for (int kk = 0; kk < 4; ++kk){
        short8 af[2], bfr[4];
        int s = u * 2 + (kk >> 1);
        int c8 = ((kk & 1) * 4 + quad) ^ rsw8;
#pragma unroll
        for (int mt = 0; mt < 2; ++mt)
          af[mt] = *(const short8*)(Ys + s * 4096 + (mh + mt*16 + l16) * 64 + (c8 << 3));
        int c16 = (kk * 4 + quad) ^ l16;
#pragma unroll
        for (int i = 0; i < 4; ++i)
          bfr[i] = *(const short8*)(Wb + ((2*i + wc) * 16 + l16) * 128 + (c16 << 3));
#pragma unroll
        for (int mt = 0; mt < 2; ++mt)
#pragma unroll
          for (int i = 0; i < 4; ++i)
            acc1[mt][i] = __builtin_amdgcn_mfma_f32_16x16x32_bf16(af[mt], bfr[i], acc1[mt][i], 0, 0, 0);
      }
      __syncthreads();
      pb ^= 1;
    }
    // -------- gelu + write h tile to Hs -----------------------------------
#pragma unroll
    for (int i = 0; i < 4; ++i){
      int nl = (2*i + wc) * 16 + l16;
      float bv = b1[j * 128 + nl];
#pragma unroll
      for (int mt = 0; mt < 2; ++mt){
#pragma unroll
        for (int r = 0; r < 4; ++r){
          int m = mh + mt*16 + quad*4 + r;
          float v = gelu_fast(acc1[mt][i][r] + bv);
          Hs[(nl >> 6) * 4096 + m * 64 + ((((nl >> 3) & 7) ^ (m & 7)) << 3) + (nl & 7)] = f2bf(v);
        }
        acc1[mt][i] = zero;
      }
    }
    __syncthreads();
    // -------- phase 2: acc2 += h_tile @ W2chunk (UNROLLED, ds compile-time)
#pragma unroll
    for (int ds = 0; ds < 3; ++ds){
      if (ds < 2)          stage16(W2T + (size_t)(ds + 1) * 128 * HIDN + (size_t)j * 128, HIDN, Wst + (pb ^ 1) * 16384);
      else if (j + 1 < NJ) stage16(W1T + (size_t)(j + 1) * 128 * 384, 384, Wst + (pb ^ 1) * 16384);
      const u16* Wb = Wst + pb * 16384;
#pragma unroll
      for (int kk = 0; kk < 4; ++kk){
        short8 af[2], bfr[4];
        int kh = kk >> 1;
        int c8 = ((kk & 1) * 4 + quad) ^ rsw8;
#pragma unroll
        for (int mt = 0; mt < 2; ++mt)
          af[mt] = *(const short8*)(Hs + kh * 4096 + (mh + mt*16 + l16) * 64 + (c8 << 3));
        int c16 = (kk * 4 + quad) ^ l16;
#pragma unroll
        for (int i = 0; i < 4; ++i)
          bfr[i] = *(const short8*)(Wb + ((2*i + wc) * 16 + l16) * 128 + (c16 << 3));
#pragma unroll
        for (int mt = 0; mt < 2; ++mt)
#pragma unroll
          for (int i = 0; i < 4; ++i)
            acc2[mt][ds*4 + i] = __builtin_amdgcn_mfma_f32_16x16x32_bf16(af[mt], bfr[i], acc2[mt][ds*4 + i], 0, 0, 0);
      }
      __syncthreads();
      pb ^= 1;
    }
  }

  // -------- epilogue: 64 rows x 384 cols ----------------------------------
#pragma unroll
  for (int mt = 0; mt < 2; ++mt){
#pragma unroll
    for (int t = 0; t < 12; ++t){
      int ds = t >> 2, i = t & 3;
      int d = ds * 128 + (2*i + wc) * 16 + l16;
      float bv = b2[d];
#pragma unroll
      for (int r = 0; r < 4; ++r){
        size_t off = (m0 + mh + mt*16 + quad*4 + r) * 384 + d;
        float v = acc2[mt][t][r] + bv;
        if (EPI == 0) ((u16*)out)[off] = f2bf(v);
        else          ((float*)out)[off] = x2[off] + v;
      }
    }
  }
}

extern "C" void kernel_launch(void* const* d_in, const int* in_sizes, int n_in,
                              void* d_out, int out_size, void* d_ws, size_t ws_size,
                              hipStream_t stream) {
  const int W11 = DIM * HID;   // 589824
  const float* x   = (const float*)d_in[0];
  const float* n1s = (const float*)d_in[1];
  const float* n1b = (const float*)d_in[2];
  const float* n2s = (const float*)d_in[3];
  const float* n2b = (const float*)d_in[4];
  const float* qw  = (const float*)d_in[5];
  const float* tw1 = (const float*)d_in[6] + 4 * W11;  // titan_w1[4]
  const float* tb1 = (const float*)d_in[7] + 4 * HID;  // titan_b1[4]
  const float* tw2 = (const float*)d_in[8] + 4 * W11;  // titan_w2[4]
  const float* tb2 = (const float*)d_in[9] + 4 * DIM;  // titan_b2[4]
  const float* ow  = (const float*)d_in[10];
  const float* ob  = (const float*)d_in[11];
  const float* cw1 = (const float*)d_in[12];
  const float* cb1 = (const float*)d_in[13];            // [3][1536] = flat [4608]
  const float* cw2 = (const float*)d_in[14];
  const float* cb2 = (const float*)d_in[15];
  const int* Tp = (const int*)d_in[16];
  const int* Hp = (const int*)d_in[17];
  const int* Wp = (const int*)d_in[18];
  const int M = in_sizes[0] / DIM;   // 16384 tokens

  // workspace layout (bytes), ~47.8 MB total
  char* ws = (char*)d_ws;
  u16*  y    = (u16*) (ws + 0);          // M x 384 bf16
  float* x2  = (float*)(ws + 12582912);  // M x 384 f32
  u16*  qwT  = (u16*) (ws + 37748736);   // 384 x 384
  u16*  owT  = (u16*) (ws + 38043648);   // 384 x 384
  u16*  w1T  = (u16*) (ws + 38338560);   // 1536 x 384
  u16*  w2T  = (u16*) (ws + 39518208);   // 384 x 1536
  u16*  cw1T = (u16*) (ws + 40697856);   // 4608 x 384 (3 stacked)
  u16*  cw2T = (u16*) (ws + 44236800);   // 384 x 4608 (k-stacked)
  float* cb2s = (float*)(ws + 47775744); // 384 f32
  u16*  qb   = (u16*)d_out;              // bf16 scratch: q -> t1; final f32 out
  if (ws_size < 47777280u) return;

  // 1. weight transposes to [out][in] bf16
  transpose_kernel<384,384><<<dim3(12,12,2),256,0,stream>>>(
      qw, ow, qw, qw, qwT, owT, qwT, qwT, 384);
  transpose_kernel<384,1536><<<dim3(48,12,4),256,0,stream>>>(
      tw1, cw1, cw1 + W11, cw1 + 2*W11, w1T, cw1T, cw1T + W11, cw1T + 2*W11, 384);
  transpose_kernel<1536,384><<<dim3(12,48,1),256,0,stream>>>(
      tw2, tw2, tw2, tw2, w2T, w2T, w2T, w2T, 1536);
  transpose_kernel<1536,384><<<dim3(12,48,3),256,0,stream>>>(
      cw2, cw2 + W11, cw2 + 2*W11, cw2, cw2T, cw2T + 1536, cw2T + 3072, cw2T, 4608);
  bias3_kernel<<<1,384,0,stream>>>(cb2, cb2s);

  // 2. y = LN1(x)
  ln_kernel<<<M/4,256,0,stream>>>(x, n1s, n1b, y);
  // 3. q = y @ q_w   (bf16, into d_out)
  gemm_kernel<64,384,384,E_NONE><<<dim3(M/64,3),256,0,stream>>>(y, qwT, qb, nullptr, nullptr, nullptr);
  // 4. RoPE(q) in-place
  rope_kernel<<<(M*192)/256,256,0,stream>>>(qb, Tp, Hp, Wp, M);
  // 5. t1 = gelu(q @ w1 + b1) @ w2 + b2   (fused, in-place in d_out)
  fused_mlp_kernel<1536,0><<<M/64,256,0,stream>>>(qb, w1T, tb1, w2T, tb2, qb, nullptr);
  // 6. x2 = x + t1 @ out_w + out_b   (f32)
  gemm_kernel<64,384,384,E_RES_F32><<<dim3(M/64,3),256,0,stream>>>(qb, owT, nullptr, ob, x, x2);
  // 7. y2 = LN2(x2)
  ln_kernel<<<M/4,256,0,stream>>>(x2, n2s, n2b, y);
  // 8. out = x2 + sum_i gelu(y2 @ cw1_i + cb1_i) @ cw2_i + cb2_i   (fused, f32)
  fused_mlp_kernel<4608,1><<<M/64,256,0,stream>>>(y, cw1T, cb1, cw2T, cb2s, d_out, x2);
}

// Round 10
// 446.379 us; speedup vs baseline: 2.4305x; 1.1854x over previous
//
#include <hip/hip_runtime.h>
#include <math.h>

typedef unsigned short u16;
typedef unsigned int u32;
typedef __attribute__((ext_vector_type(8))) short short8;   // 8 bf16 (4 VGPRs)
typedef __attribute__((ext_vector_type(4))) float f32x4;

#define DIM 384
#define HID 1536

static __device__ __forceinline__ float bf2f(u32 b){ return __uint_as_float(b << 16); }
static __device__ __forceinline__ u16 f2bf(float f){
  u32 u = __float_as_uint(f);
  u32 r = (u + 0x7fffu + ((u >> 16) & 1u)) >> 16;
  return (u16)r;
}
// tanh-form GELU via sigmoid; |err| ~1e-4 in our operating range
static __device__ __forceinline__ float gelu_fast(float v){
  float u = v * fmaf(0.0713548162726f, v * v, 1.59576912161f);
  float e = exp2f(-1.44269504089f * u);
  return v * __builtin_amdgcn_rcpf(1.0f + e);
}
// async global->LDS, 16B/lane; LDS dest = wave-uniform base + lane*16
static __device__ __forceinline__ void gload_lds16(const u16* g, u16* l){
  __builtin_amdgcn_global_load_lds(
      (__attribute__((address_space(1))) void*)(void*)const_cast<u16*>(g),
      (__attribute__((address_space(3))) void*)(void*)l, 16, 0, 0);
}

// ---------------- LayerNorm: f32 in, bf16 out ------------------------------
__global__ __launch_bounds__(256) void ln_kernel(const float* __restrict__ x,
    const float* __restrict__ sc, const float* __restrict__ bi, u16* __restrict__ y){
  int lane = threadIdx.x & 63;
  int row = blockIdx.x * 4 + (threadIdx.x >> 6);
  const float* xr = x + (size_t)row * DIM;
  float v[6];
  float s = 0.f, sq = 0.f;
#pragma unroll
  for (int i = 0; i < 6; ++i){
    float f = xr[lane + 64*i];
    v[i] = f; s += f; sq += f*f;
  }
#pragma unroll
  for (int o = 1; o < 64; o <<= 1){ s += __shfl_xor(s, o); sq += __shfl_xor(sq, o); }
  float mean = s * (1.0f/DIM);
  float var = sq * (1.0f/DIM) - mean*mean;
  float inv = rsqrtf(var + 1e-5f);
  u16* yr = y + (size_t)row * DIM;
#pragma unroll
  for (int i = 0; i < 6; ++i){
    int c = lane + 64*i;
    yr[c] = f2bf((v[i] - mean) * inv * sc[c] + bi[c]);
  }
}

// ---------------- 3D RoPE, in-place on q (bf16) ----------------------------
__global__ __launch_bounds__(256) void rope_kernel(u16* __restrict__ q,
    const int* __restrict__ Tp, const int* __restrict__ Hp, const int* __restrict__ Wp,
    int Mtok){
  int idx = blockIdx.x * 256 + threadIdx.x;   // one thread per rotated pair
  int tok = idx / 192;                         // 192 pairs per token
  if (tok >= Mtok) return;
  int p = idx - tok * 192;
  int H = *Hp, W = *Wp, T = *Tp;
  int HW = H * W;
  int Ns = T * HW;
  int n = tok % Ns;
  int head = p / 12;
  int pp = p - head * 12;
  int s = pp >> 2, f = pp & 3;
  float pos;
  if (s == 0)      pos = (float)(n / HW);
  else if (s == 1) pos = (float)((n / W) % H);
  else             pos = (float)(n % W);
  const float LOG2_10000 = 13.28771237954945f;
  float inv = exp2f(-0.25f * (float)f * LOG2_10000);
  float ang = pos * inv;
  float sn = sinf(ang), cs = cosf(ang);
  size_t base = (size_t)tok * DIM + head * 24 + s * 8 + 2 * f;
  u32 u = *(u32*)(q + base);
  float x1 = bf2f(u & 0xffffu), x2 = bf2f(u >> 16);
  float y1 = x1 * cs - x2 * sn;
  float y2 = x1 * sn + x2 * cs;
  *(u32*)(q + base) = (u32)f2bf(y1) | ((u32)f2bf(y2) << 16);
}

// -------- weight transpose+convert: f32 in[R][C] -> bf16 out[C][R'] --------
template<int R, int C>
__global__ __launch_bounds__(256) void transpose_kernel(
    const float* __restrict__ s0, const float* __restrict__ s1,
    const float* __restrict__ s2, const float* __restrict__ s3,
    u16* __restrict__ d0, u16* __restrict__ d1, u16* __restrict__ d2, u16* __restrict__ d3,
    int dstStride){
  const float* src = (blockIdx.z == 0) ? s0 : (blockIdx.z == 1) ? s1 : (blockIdx.z == 2) ? s2 : s3;
  u16* dst         = (blockIdx.z == 0) ? d0 : (blockIdx.z == 1) ? d1 : (blockIdx.z == 2) ? d2 : d3;
  __shared__ u16 t[32][33];
  int tx = threadIdx.x & 31, ty = threadIdx.x >> 5;  // 32 x 8
  int r0 = blockIdx.y * 32, c0 = blockIdx.x * 32;
#pragma unroll
  for (int i = 0; i < 4; ++i)
    t[ty + 8*i][tx] = f2bf(src[(size_t)(r0 + ty + 8*i) * C + c0 + tx]);
  __syncthreads();
#pragma unroll
  for (int i = 0; i < 4; ++i)
    dst[(size_t)(c0 + ty + 8*i) * dstStride + r0 + tx] = t[tx][ty + 8*i];
}

// ---------------- sum 3 bias vectors of 384 --------------------------------
__global__ void bias3_kernel(const float* __restrict__ b, float* __restrict__ o){
  int n = threadIdx.x;
  o[n] = b[n] + b[384 + n] + b[768 + n];
}

// ---------------- MFMA GEMM: C = A[M,K](bf16) @ Bt[N,K](bf16)^T ------------
// R7-verified core (global_load_lds w16 staging + XOR swizzle, 0 conflicts).
// NEW: LDS-staged coalesced epilogue — acc -> padded LDS tile -> 16B-chunk
// row-major stores (scalar u16 stores were 32B/transaction: 1.26 TB/s cap).
enum { E_NONE = 0, E_BIAS = 1, E_BIAS_GELU = 2, E_RES_F32 = 3, E_ACC_F32 = 4, E_FINAL = 5 };

template<int BM, int N, int K, int EPI>
__global__ __launch_bounds__(256) void gemm_kernel(
    const u16* __restrict__ A, const u16* __restrict__ Bt,
    void* __restrict__ Cv, const float* __restrict__ bias,
    const float* __restrict__ res, float* __restrict__ accbuf){
  constexpr int BN = 128, BK = 64;
  constexpr int MT = BM / 32, NT = 4;
  constexpr int AIT = BM / 32, BIT = 4;
  // smem: staging As[BM*64] ++ Bs[128*64]; epilogue reuses as padded C tile.
  // 16896 u16 = 33.8 KB covers: staging (<=16384), bf16 tile BM*132,
  // f32 tile 64*132 (f32 EPIs are BM=64 only).
  __shared__ __align__(16) u16 smem[16896];
  u16* As = smem;
  u16* Bs = smem + BM * 64;
  const int tid = threadIdx.x;
  const int lane = tid & 63;
  const int wv = tid >> 6;
  const int wm = (wv >> 1) * (BM / 2);
  const int wn = (wv & 1) * 64;
  const int quad = lane >> 4;
  const int l16 = lane & 15;
  const int rsw = l16 & 7;
  const size_t m0 = (size_t)blockIdx.x * BM;
  const int n0 = blockIdx.y * BN;
  const int srow = lane >> 3;
  const int scol = ((lane & 7) ^ srow) * 8;

  f32x4 acc[MT][NT];
  const f32x4 zero = {0.f, 0.f, 0.f, 0.f};
#pragma unroll
  for (int mt = 0; mt < MT; ++mt)
#pragma unroll
    for (int nt = 0; nt < NT; ++nt) acc[mt][nt] = zero;

  for (int kt = 0; kt < K; kt += BK){
#pragma unroll
    for (int i = 0; i < AIT; ++i){
      int seg = i * 4 + wv;
      gload_lds16(A + (m0 + (size_t)(seg * 8 + srow)) * K + kt + scol, As + seg * 512);
    }
#pragma unroll
    for (int i = 0; i < BIT; ++i){
      int seg = i * 4 + wv;
      gload_lds16(Bt + (size_t)(n0 + seg * 8 + srow) * K + kt + scol, Bs + seg * 512);
    }
    __syncthreads();
#pragma unroll
    for (int kk = 0; kk < 2; ++kk){
      short8 af[MT], bfr[NT];
#pragma unroll
      for (int mt = 0; mt < MT; ++mt)
        af[mt] = *(const short8*)(As + (wm + mt*16 + l16) * BK + (((kk*4 + quad) ^ rsw) << 3));
#pragma unroll
      for (int nt = 0; nt < NT; ++nt)
        bfr[nt] = *(const short8*)(Bs + (wn + nt*16 + l16) * BK + (((kk*4 + quad) ^ rsw) << 3));
#pragma unroll
      for (int mt = 0; mt < MT; ++mt)
#pragma unroll
        for (int nt = 0; nt < NT; ++nt)
          acc[mt][nt] = __builtin_amdgcn_mfma_f32_16x16x32_bf16(af[mt], bfr[nt], acc[mt][nt], 0, 0, 0);
    }
    __syncthreads();   // also: smem free for epilogue reuse after last iter
  }

  // ---- epilogue: acc -> padded LDS tile -> coalesced 16B stores ----------
  if (EPI == E_NONE || EPI == E_BIAS || EPI == E_BIAS_GELU){
    u16* Cs = smem;                       // [BM][132] u16
#pragma unroll
    for (int mt = 0; mt < MT; ++mt){
#pragma unroll
      for (int nt = 0; nt < NT; ++nt){
        int ncol = wn + nt*16 + l16;
        float bv = (EPI != E_NONE) ? bias[n0 + ncol] : 0.f;
#pragma unroll
        for (int r = 0; r < 4; ++r){
          float vv = acc[mt][nt][r];
          float v = (EPI == E_NONE) ? vv : (EPI == E_BIAS ? vv + bv : gelu_fast(vv + bv));
          Cs[(wm + mt*16 + quad*4 + r) * 132 + ncol] = f2bf(v);
        }
      }
    }
    __syncthreads();
#pragma unroll
    for (int c = 0; c < BM/16; ++c){      // 16B chunks: BM*128*2B / 256 lanes
      int idx = c * 256 + tid;
      int row = idx >> 4, ch = idx & 15;
      short8 v = *(const short8*)(Cs + row * 132 + ch * 8);
      *(short8*)((u16*)Cv + (m0 + row) * N + n0 + ch * 8) = v;
    }
  } else {
    // f32 epilogues (BM==64 in all uses): [64][132] f32 tile
    float* Cs = (float*)smem;
#pragma unroll
    for (int mt = 0; mt < MT; ++mt){
#pragma unroll
      for (int nt = 0; nt < NT; ++nt){
        int ncol = wn + nt*16 + l16;
        float bv = bias[n0 + ncol];
#pragma unroll
        for (int r = 0; r < 4; ++r)
          Cs[(wm + mt*16 + quad*4 + r) * 132 + ncol] = acc[mt][nt][r] + bv;
      }
    }
    __syncthreads();
#pragma unroll
    for (int c = 0; c < BM/8; ++c){       // f32x4 chunks: BM*128*4B / 256 lanes
      int idx = c * 256 + tid;
      int row = idx >> 5, ch = idx & 31;
      f32x4 v = *(const f32x4*)(Cs + row * 132 + ch * 4);
      size_t off = (m0 + row) * N + n0 + ch * 4;
      if (EPI == E_RES_F32){
        f32x4 rr = *(const f32x4*)(res + off);
        *(f32x4*)(accbuf + off) = v + rr;
      } else if (EPI == E_ACC_F32){
        f32x4 aa = *(const f32x4*)(accbuf + off);
        *(f32x4*)(accbuf + off) = aa + v;
      } else { // E_FINAL
        f32x4 aa = *(const f32x4*)(accbuf + off);
        *(f32x4*)((float*)Cv + off) = aa + v;
      }
    }
  }
}

extern "C" void kernel_launch(void* const* d_in, const int* in_sizes, int n_in,
                              void* d_out, int out_size, void* d_ws, size_t ws_size,
                              hipStream_t stream) {
  const int W11 = DIM * HID;   // 589824
  const float* x   = (const float*)d_in[0];
  const float* n1s = (const float*)d_in[1];
  const float* n1b = (const float*)d_in[2];
  const float* n2s = (const float*)d_in[3];
  const float* n2b = (const float*)d_in[4];
  const float* qw  = (const float*)d_in[5];
  const float* tw1 = (const float*)d_in[6] + 4 * W11;  // titan_w1[4]
  const float* tb1 = (const float*)d_in[7] + 4 * HID;  // titan_b1[4]
  const float* tw2 = (const float*)d_in[8] + 4 * W11;  // titan_w2[4]
  const float* tb2 = (const float*)d_in[9] + 4 * DIM;  // titan_b2[4]
  const float* ow  = (const float*)d_in[10];
  const float* ob  = (const float*)d_in[11];
  const float* cw1 = (const float*)d_in[12];
  const float* cb1 = (const float*)d_in[13];
  const float* cw2 = (const float*)d_in[14];
  const float* cb2 = (const float*)d_in[15];
  const int* Tp = (const int*)d_in[16];
  const int* Hp = (const int*)d_in[17];
  const int* Wp = (const int*)d_in[18];
  const int M = in_sizes[0] / DIM;   // 16384 tokens
  const bool fused = (ws_size >= 198772224u);   // fixed per problem -> graph-safe

  char* ws = (char*)d_ws;
  u16 *y, *h, *qwT, *owT, *w1T, *w2T, *cw1T, *cw2T;
  float *x2, *cb2s = nullptr;
  u16* qb = (u16*)d_out;   // bf16 scratch: q, then t1; overwritten by E_FINAL f32
  if (fused){
    y    = (u16*) (ws + 0);            // M x 384 bf16
    h    = (u16*) (ws + 12582912);     // M x 4608 bf16 (h_cat)
    x2   = (float*)(ws + 163577856);   // M x 384 f32
    qwT  = (u16*) (ws + 188743680);    // 384 x 384
    owT  = (u16*) (ws + 189038592);    // 384 x 384
    w1T  = (u16*) (ws + 189333504);    // 1536 x 384
    w2T  = (u16*) (ws + 190513152);    // 384 x 1536
    cw1T = (u16*) (ws + 191692800);    // 4608 x 384 (3 stacked, contiguous)
    cw2T = (u16*) (ws + 195231744);    // 384 x 4608 (K-stacked)
    cb2s = (float*)(ws + 198770688);   // 384 f32
  } else {
    if (ws_size < 98107392u) return;
    y    = (u16*) (ws + 0);
    h    = (u16*) (ws + 12582912);     // M x 1536 bf16
    x2   = (float*)(ws + 62914560);
    qwT  = (u16*) (ws + 88080384);
    owT  = (u16*) (ws + 88375296);
    w1T  = (u16*) (ws + 88670208);
    w2T  = (u16*) (ws + 89849856);
    cw1T = (u16*) (ws + 91029504);     // 3 x (1536 x 384)
    cw2T = (u16*) (ws + 94568448);     // 3 x (384 x 1536)
  }

  // 1. transpose+convert weights to bf16 [N][K]
  transpose_kernel<384,384><<<dim3(12,12,2),256,0,stream>>>(
      qw, ow, qw, qw, qwT, owT, qwT, qwT, 384);
  transpose_kernel<384,1536><<<dim3(48,12,4),256,0,stream>>>(
      tw1, cw1, cw1 + W11, cw1 + 2*W11, w1T, cw1T, cw1T + W11, cw1T + 2*W11, 384);
  if (fused){
    transpose_kernel<1536,384><<<dim3(12,48,1),256,0,stream>>>(
        tw2, tw2, tw2, tw2, w2T, w2T, w2T, w2T, 1536);
    transpose_kernel<1536,384><<<dim3(12,48,3),256,0,stream>>>(
        cw2, cw2 + W11, cw2 + 2*W11, cw2, cw2T, cw2T + 1536, cw2T + 3072, cw2T, 4608);
    bias3_kernel<<<1,384,0,stream>>>(cb2, cb2s);
  } else {
    transpose_kernel<1536,384><<<dim3(12,48,4),256,0,stream>>>(
        tw2, cw2, cw2 + W11, cw2 + 2*W11, w2T, cw2T, cw2T + W11, cw2T + 2*W11, 1536);
  }

  // 2. y = LN1(x)
  ln_kernel<<<M/4,256,0,stream>>>(x, n1s, n1b, y);
  // 3. q = y @ q_w   (bf16, into d_out)
  gemm_kernel<64,384,384,E_NONE><<<dim3(M/64,3),256,0,stream>>>(y, qwT, qb, nullptr, nullptr, nullptr);
  // 4. RoPE(q) in-place
  rope_kernel<<<(M*192)/256,256,0,stream>>>(qb, Tp, Hp, Wp, M);
  // 5. h = gelu(q @ w1 + b1)
  gemm_kernel<128,1536,384,E_BIAS_GELU><<<dim3(M/128,12),256,0,stream>>>(qb, w1T, h, tb1, nullptr, nullptr);
  // 6. t1 = h @ w2 + b2   (bf16, into d_out)
  gemm_kernel<64,384,1536,E_BIAS><<<dim3(M/64,3),256,0,stream>>>(h, w2T, qb, tb2, nullptr, nullptr);
  // 7. x2 = x + t1 @ out_w + out_b   (f32)
  gemm_kernel<64,384,384,E_RES_F32><<<dim3(M/64,3),256,0,stream>>>(qb, owT, nullptr, ob, x, x2);
  // 8. y2 = LN2(x2)
  ln_kernel<<<M/4,256,0,stream>>>(x2, n2s, n2b, y);
  // 9. cms MLPs
  if (fused){
    gemm_kernel<128,4608,384,E_BIAS_GELU><<<dim3(M/128,36),256,0,stream>>>(
        y, cw1T, h, cb1, nullptr, nullptr);
    gemm_kernel<64,384,4608,E_FINAL><<<dim3(M/64,3),256,0,stream>>>(
        h, cw2T, d_out, cb2s, nullptr, x2);
  } else {
    for (int i = 0; i < 3; ++i){
      gemm_kernel<128,1536,384,E_BIAS_GELU><<<dim3(M/128,12),256,0,stream>>>(
          y, cw1T + i*W11, h, cb1 + i*HID, nullptr, nullptr);
      if (i < 2)
        gemm_kernel<64,384,1536,E_ACC_F32><<<dim3(M/64,3),256,0,stream>>>(
            h, cw2T + i*W11, nullptr, cb2 + i*DIM, nullptr, x2);
      else
        gemm_kernel<64,384,1536,E_FINAL><<<dim3(M/64,3),256,0,stream>>>(
            h, cw2T + i*W11, d_out, cb2 + i*DIM, nullptr, x2);
    }
  }
}

// Round 11
// 393.081 us; speedup vs baseline: 2.7600x; 1.1356x over previous
//
#include <hip/hip_runtime.h>
#include <math.h>

typedef unsigned short u16;
typedef unsigned int u32;
typedef __attribute__((ext_vector_type(8))) short short8;   // 8 bf16 (4 VGPRs)
typedef __attribute__((ext_vector_type(4))) float f32x4;

#define DIM 384
#define HID 1536

static __device__ __forceinline__ float bf2f(u32 b){ return __uint_as_float(b << 16); }
static __device__ __forceinline__ u16 f2bf(float f){
  u32 u = __float_as_uint(f);
  u32 r = (u + 0x7fffu + ((u >> 16) & 1u)) >> 16;
  return (u16)r;
}
// tanh-form GELU via sigmoid; |err| ~1e-4 in our operating range
static __device__ __forceinline__ float gelu_fast(float v){
  float u = v * fmaf(0.0713548162726f, v * v, 1.59576912161f);
  float e = exp2f(-1.44269504089f * u);
  return v * __builtin_amdgcn_rcpf(1.0f + e);
}
// async global->LDS, 16B/lane; LDS dest = wave-uniform base + lane*16
static __device__ __forceinline__ void gload_lds16(const u16* g, u16* l){
  __builtin_amdgcn_global_load_lds(
      (__attribute__((address_space(1))) void*)(void*)const_cast<u16*>(g),
      (__attribute__((address_space(3))) void*)(void*)l, 16, 0, 0);
}

// ---------------- LayerNorm: f32 in, bf16 out ------------------------------
__global__ __launch_bounds__(256) void ln_kernel(const float* __restrict__ x,
    const float* __restrict__ sc, const float* __restrict__ bi, u16* __restrict__ y){
  int lane = threadIdx.x & 63;
  int row = blockIdx.x * 4 + (threadIdx.x >> 6);
  const float* xr = x + (size_t)row * DIM;
  float v[6];
  float s = 0.f, sq = 0.f;
#pragma unroll
  for (int i = 0; i < 6; ++i){
    float f = xr[lane + 64*i];
    v[i] = f; s += f; sq += f*f;
  }
#pragma unroll
  for (int o = 1; o < 64; o <<= 1){ s += __shfl_xor(s, o); sq += __shfl_xor(sq, o); }
  float mean = s * (1.0f/DIM);
  float var = sq * (1.0f/DIM) - mean*mean;
  float inv = rsqrtf(var + 1e-5f);
  u16* yr = y + (size_t)row * DIM;
#pragma unroll
  for (int i = 0; i < 6; ++i){
    int c = lane + 64*i;
    yr[c] = f2bf((v[i] - mean) * inv * sc[c] + bi[c]);
  }
}

// ---------------- 3D RoPE, in-place on q (bf16) ----------------------------
__global__ __launch_bounds__(256) void rope_kernel(u16* __restrict__ q,
    const int* __restrict__ Tp, const int* __restrict__ Hp, const int* __restrict__ Wp,
    int Mtok){
  int idx = blockIdx.x * 256 + threadIdx.x;   // one thread per rotated pair
  int tok = idx / 192;                         // 192 pairs per token
  if (tok >= Mtok) return;
  int p = idx - tok * 192;
  int H = *Hp, W = *Wp, T = *Tp;
  int HW = H * W;
  int Ns = T * HW;
  int n = tok % Ns;
  int head = p / 12;
  int pp = p - head * 12;
  int s = pp >> 2, f = pp & 3;
  float pos;
  if (s == 0)      pos = (float)(n / HW);
  else if (s == 1) pos = (float)((n / W) % H);
  else             pos = (float)(n % W);
  const float LOG2_10000 = 13.28771237954945f;
  float inv = exp2f(-0.25f * (float)f * LOG2_10000);
  float ang = pos * inv;
  float sn = sinf(ang), cs = cosf(ang);
  size_t base = (size_t)tok * DIM + head * 24 + s * 8 + 2 * f;
  u32 u = *(u32*)(q + base);
  float x1 = bf2f(u & 0xffffu), x2 = bf2f(u >> 16);
  float y1 = x1 * cs - x2 * sn;
  float y2 = x1 * sn + x2 * cs;
  *(u32*)(q + base) = (u32)f2bf(y1) | ((u32)f2bf(y2) << 16);
}

// -------- weight transpose+convert: f32 in[R][C] -> bf16 out[C][R'] --------
template<int R, int C>
__global__ __launch_bounds__(256) void transpose_kernel(
    const float* __restrict__ s0, const float* __restrict__ s1,
    const float* __restrict__ s2, const float* __restrict__ s3,
    u16* __restrict__ d0, u16* __restrict__ d1, u16* __restrict__ d2, u16* __restrict__ d3,
    int dstStride){
  const float* src = (blockIdx.z == 0) ? s0 : (blockIdx.z == 1) ? s1 : (blockIdx.z == 2) ? s2 : s3;
  u16* dst         = (blockIdx.z == 0) ? d0 : (blockIdx.z == 1) ? d1 : (blockIdx.z == 2) ? d2 : d3;
  __shared__ u16 t[32][33];
  int tx = threadIdx.x & 31, ty = threadIdx.x >> 5;  // 32 x 8
  int r0 = blockIdx.y * 32, c0 = blockIdx.x * 32;
#pragma unroll
  for (int i = 0; i < 4; ++i)
    t[ty + 8*i][tx] = f2bf(src[(size_t)(r0 + ty + 8*i) * C + c0 + tx]);
  __syncthreads();
#pragma unroll
  for (int i = 0; i < 4; ++i)
    dst[(size_t)(c0 + ty + 8*i) * dstStride + r0 + tx] = t[tx][ty + 8*i];
}

// ---------------- sum 3 bias vectors of 384 --------------------------------
__global__ void bias3_kernel(const float* __restrict__ b, float* __restrict__ o){
  int n = threadIdx.x;
  o[n] = b[n] + b[384 + n] + b[768 + n];
}

// ---------------- MFMA GEMM (R7-exact): C = A[M,K] @ Bt[N,K]^T -------------
// global_load_lds w16 staging + XOR swizzle (0 conflicts), direct epilogue.
enum { E_NONE = 0, E_BIAS = 1, E_BIAS_GELU = 2, E_RES_F32 = 3, E_ACC_F32 = 4, E_FINAL = 5 };

template<int BM, int N, int K, int EPI>
__global__ __launch_bounds__(256) void gemm_kernel(
    const u16* __restrict__ A, const u16* __restrict__ Bt,
    void* __restrict__ Cv, const float* __restrict__ bias,
    const float* __restrict__ res, float* __restrict__ accbuf){
  constexpr int BN = 128, BK = 64;
  constexpr int MT = BM / 32, NT = 4;
  constexpr int AIT = BM / 32, BIT = 4;
  __shared__ __align__(16) u16 As[BM * BK];
  __shared__ __align__(16) u16 Bs[BN * BK];
  const int tid = threadIdx.x;
  const int lane = tid & 63;
  const int wv = tid >> 6;
  const int wm = (wv >> 1) * (BM / 2);
  const int wn = (wv & 1) * 64;
  const int quad = lane >> 4;
  const int l16 = lane & 15;
  const int rsw = l16 & 7;
  const size_t m0 = (size_t)blockIdx.x * BM;
  const int n0 = blockIdx.y * BN;
  const int srow = lane >> 3;
  const int scol = ((lane & 7) ^ srow) * 8;

  f32x4 acc[MT][NT];
  const f32x4 zero = {0.f, 0.f, 0.f, 0.f};
#pragma unroll
  for (int mt = 0; mt < MT; ++mt)
#pragma unroll
    for (int nt = 0; nt < NT; ++nt) acc[mt][nt] = zero;

  for (int kt = 0; kt < K; kt += BK){
#pragma unroll
    for (int i = 0; i < AIT; ++i){
      int seg = i * 4 + wv;
      gload_lds16(A + (m0 + (size_t)(seg * 8 + srow)) * K + kt + scol, As + seg * 512);
    }
#pragma unroll
    for (int i = 0; i < BIT; ++i){
      int seg = i * 4 + wv;
      gload_lds16(Bt + (size_t)(n0 + seg * 8 + srow) * K + kt + scol, Bs + seg * 512);
    }
    __syncthreads();
#pragma unroll
    for (int kk = 0; kk < 2; ++kk){
      short8 af[MT], bfr[NT];
#pragma unroll
      for (int mt = 0; mt < MT; ++mt)
        af[mt] = *(const short8*)(As + (wm + mt*16 + l16) * BK + (((kk*4 + quad) ^ rsw) << 3));
#pragma unroll
      for (int nt = 0; nt < NT; ++nt)
        bfr[nt] = *(const short8*)(Bs + (wn + nt*16 + l16) * BK + (((kk*4 + quad) ^ rsw) << 3));
#pragma unroll
      for (int mt = 0; mt < MT; ++mt)
#pragma unroll
        for (int nt = 0; nt < NT; ++nt)
          acc[mt][nt] = __builtin_amdgcn_mfma_f32_16x16x32_bf16(af[mt], bfr[nt], acc[mt][nt], 0, 0, 0);
    }
    __syncthreads();
  }

  // epilogue: C/D mapping col = lane&15, row = quad*4 + reg  [m89-verified]
#pragma unroll
  for (int mt = 0; mt < MT; ++mt){
#pragma unroll
    for (int nt = 0; nt < NT; ++nt){
      int ncol = n0 + wn + nt*16 + l16;
      float bv = (EPI != E_NONE) ? bias[ncol] : 0.f;
      size_t mbase = m0 + wm + mt*16 + quad*4;
#pragma unroll
      for (int r = 0; r < 4; ++r){
        size_t off = (mbase + r) * N + ncol;
        float vv = acc[mt][nt][r];
        if      (EPI == E_NONE)      ((u16*)Cv)[off] = f2bf(vv);
        else if (EPI == E_BIAS)      ((u16*)Cv)[off] = f2bf(vv + bv);
        else if (EPI == E_BIAS_GELU) ((u16*)Cv)[off] = f2bf(gelu_fast(vv + bv));
        else if (EPI == E_RES_F32)   accbuf[off] = vv + bv + res[off];
        else if (EPI == E_ACC_F32)   accbuf[off] += vv + bv;
        else /* E_FINAL */           ((float*)Cv)[off] = accbuf[off] + vv + bv;
      }
    }
  }
}

// ---------------- Up-GEMM: C = gelu(A @ Bt^T + bias), fat N-tile -----------
// BM=64, BN=256, BK=64; 256 threads; wave tile 32x128 (MT=2, NT=8).
// Per wave per K-iter: 32 MFMA vs 16 in gemm_kernel — double the
// MFMA:(ds_read+staging) ratio. LDS 40KB; target 3 blocks/CU (12 waves).
template<int N, int K>
__global__ __launch_bounds__(256, 3) void gemm_up_kernel(
    const u16* __restrict__ A, const u16* __restrict__ Bt,
    u16* __restrict__ C, const float* __restrict__ bias){
  constexpr int BK = 64;
  __shared__ __align__(16) u16 As[64 * BK];    //  8 KB
  __shared__ __align__(16) u16 Bs[256 * BK];   // 32 KB
  const int tid = threadIdx.x;
  const int lane = tid & 63;
  const int wv = tid >> 6;
  const int wm = (wv >> 1) * 32;     // 0 or 32
  const int wn = (wv & 1) * 128;     // 0 or 128
  const int quad = lane >> 4;
  const int l16 = lane & 15;
  const int rsw = l16 & 7;
  const size_t m0 = (size_t)blockIdx.x * 64;
  const int n0 = blockIdx.y * 256;
  const int srow = lane >> 3;
  const int scol = ((lane & 7) ^ srow) * 8;

  f32x4 acc[2][8];
  const f32x4 zero = {0.f, 0.f, 0.f, 0.f};
#pragma unroll
  for (int mt = 0; mt < 2; ++mt)
#pragma unroll
    for (int nt = 0; nt < 8; ++nt) acc[mt][nt] = zero;

  for (int kt = 0; kt < K; kt += BK){
    // A: 8 segs (2/wave); B: 32 segs (8/wave)
#pragma unroll
    for (int i = 0; i < 2; ++i){
      int seg = i * 4 + wv;
      gload_lds16(A + (m0 + (size_t)(seg * 8 + srow)) * K + kt + scol, As + seg * 512);
    }
#pragma unroll
    for (int i = 0; i < 8; ++i){
      int seg = i * 4 + wv;
      gload_lds16(Bt + (size_t)(n0 + seg * 8 + srow) * K + kt + scol, Bs + seg * 512);
    }
    __syncthreads();
#pragma unroll
    for (int kk = 0; kk < 2; ++kk){
      short8 af[2], bfr[8];
#pragma unroll
      for (int mt = 0; mt < 2; ++mt)
        af[mt] = *(const short8*)(As + (wm + mt*16 + l16) * BK + (((kk*4 + quad) ^ rsw) << 3));
#pragma unroll
      for (int nt = 0; nt < 8; ++nt)
        bfr[nt] = *(const short8*)(Bs + (wn + nt*16 + l16) * BK + (((kk*4 + quad) ^ rsw) << 3));
#pragma unroll
      for (int mt = 0; mt < 2; ++mt)
#pragma unroll
        for (int nt = 0; nt < 8; ++nt)
          acc[mt][nt] = __builtin_amdgcn_mfma_f32_16x16x32_bf16(af[mt], bfr[nt], acc[mt][nt], 0, 0, 0);
    }
    __syncthreads();
  }

  // epilogue: direct stores (measured faster than LDS-staged in R10)
#pragma unroll
  for (int mt = 0; mt < 2; ++mt){
#pragma unroll
    for (int nt = 0; nt < 8; ++nt){
      int ncol = n0 + wn + nt*16 + l16;
      float bv = bias[ncol];
      size_t mbase = m0 + wm + mt*16 + quad*4;
#pragma unroll
      for (int r = 0; r < 4; ++r)
        C[(mbase + r) * N + ncol] = f2bf(gelu_fast(acc[mt][nt][r] + bv));
    }
  }
}

extern "C" void kernel_launch(void* const* d_in, const int* in_sizes, int n_in,
                              void* d_out, int out_size, void* d_ws, size_t ws_size,
                              hipStream_t stream) {
  const int W11 = DIM * HID;   // 589824
  const float* x   = (const float*)d_in[0];
  const float* n1s = (const float*)d_in[1];
  const float* n1b = (const float*)d_in[2];
  const float* n2s = (const float*)d_in[3];
  const float* n2b = (const float*)d_in[4];
  const float* qw  = (const float*)d_in[5];
  const float* tw1 = (const float*)d_in[6] + 4 * W11;  // titan_w1[4]
  const float* tb1 = (const float*)d_in[7] + 4 * HID;  // titan_b1[4]
  const float* tw2 = (const float*)d_in[8] + 4 * W11;  // titan_w2[4]
  const float* tb2 = (const float*)d_in[9] + 4 * DIM;  // titan_b2[4]
  const float* ow  = (const float*)d_in[10];
  const float* ob  = (const float*)d_in[11];
  const float* cw1 = (const float*)d_in[12];
  const float* cb1 = (const float*)d_in[13];
  const float* cw2 = (const float*)d_in[14];
  const float* cb2 = (const float*)d_in[15];
  const int* Tp = (const int*)d_in[16];
  const int* Hp = (const int*)d_in[17];
  const int* Wp = (const int*)d_in[18];
  const int M = in_sizes[0] / DIM;   // 16384 tokens
  const bool fused = (ws_size >= 198772224u);   // fixed per problem -> graph-safe

  char* ws = (char*)d_ws;
  u16 *y, *h, *qwT, *owT, *w1T, *w2T, *cw1T, *cw2T;
  float *x2, *cb2s = nullptr;
  u16* qb = (u16*)d_out;   // bf16 scratch: q, then t1; overwritten by E_FINAL f32
  if (fused){
    y    = (u16*) (ws + 0);            // M x 384 bf16
    h    = (u16*) (ws + 12582912);     // M x 4608 bf16 (h_cat)
    x2   = (float*)(ws + 163577856);   // M x 384 f32
    qwT  = (u16*) (ws + 188743680);    // 384 x 384
    owT  = (u16*) (ws + 189038592);    // 384 x 384
    w1T  = (u16*) (ws + 189333504);    // 1536 x 384
    w2T  = (u16*) (ws + 190513152);    // 384 x 1536
    cw1T = (u16*) (ws + 191692800);    // 4608 x 384 (3 stacked, contiguous)
    cw2T = (u16*) (ws + 195231744);    // 384 x 4608 (K-stacked)
    cb2s = (float*)(ws + 198770688);   // 384 f32
  } else {
    if (ws_size < 98107392u) return;
    y    = (u16*) (ws + 0);
    h    = (u16*) (ws + 12582912);     // M x 1536 bf16
    x2   = (float*)(ws + 62914560);
    qwT  = (u16*) (ws + 88080384);
    owT  = (u16*) (ws + 88375296);
    w1T  = (u16*) (ws + 88670208);
    w2T  = (u16*) (ws + 89849856);
    cw1T = (u16*) (ws + 91029504);     // 3 x (1536 x 384)
    cw2T = (u16*) (ws + 94568448);     // 3 x (384 x 1536)
  }

  // 1. transpose+convert weights to bf16 [N][K]
  transpose_kernel<384,384><<<dim3(12,12,2),256,0,stream>>>(
      qw, ow, qw, qw, qwT, owT, qwT, qwT, 384);
  transpose_kernel<384,1536><<<dim3(48,12,4),256,0,stream>>>(
      tw1, cw1, cw1 + W11, cw1 + 2*W11, w1T, cw1T, cw1T + W11, cw1T + 2*W11, 384);
  if (fused){
    transpose_kernel<1536,384><<<dim3(12,48,1),256,0,stream>>>(
        tw2, tw2, tw2, tw2, w2T, w2T, w2T, w2T, 1536);
    transpose_kernel<1536,384><<<dim3(12,48,3),256,0,stream>>>(
        cw2, cw2 + W11, cw2 + 2*W11, cw2, cw2T, cw2T + 1536, cw2T + 3072, cw2T, 4608);
    bias3_kernel<<<1,384,0,stream>>>(cb2, cb2s);
  } else {
    transpose_kernel<1536,384><<<dim3(12,48,4),256,0,stream>>>(
        tw2, cw2, cw2 + W11, cw2 + 2*W11, w2T, cw2T, cw2T + W11, cw2T + 2*W11, 1536);
  }

  // 2. y = LN1(x)
  ln_kernel<<<M/4,256,0,stream>>>(x, n1s, n1b, y);
  // 3. q = y @ q_w   (bf16, into d_out)
  gemm_kernel<64,384,384,E_NONE><<<dim3(M/64,3),256,0,stream>>>(y, qwT, qb, nullptr, nullptr, nullptr);
  // 4. RoPE(q) in-place
  rope_kernel<<<(M*192)/256,256,0,stream>>>(qb, Tp, Hp, Wp, M);
  // 5. h = gelu(q @ w1 + b1)   (fat-N up-GEMM)
  gemm_up_kernel<1536,384><<<dim3(M/64,6),256,0,stream>>>(qb, w1T, h, tb1);
  // 6. t1 = h @ w2 + b2   (bf16, into d_out)
  gemm_kernel<64,384,1536,E_BIAS><<<dim3(M/64,3),256,0,stream>>>(h, w2T, qb, tb2, nullptr, nullptr);
  // 7. x2 = x + t1 @ out_w + out_b   (f32)
  gemm_kernel<64,384,384,E_RES_F32><<<dim3(M/64,3),256,0,stream>>>(qb, owT, nullptr, ob, x, x2);
  // 8. y2 = LN2(x2)
  ln_kernel<<<M/4,256,0,stream>>>(x2, n2s, n2b, y);
  // 9. cms MLPs
  if (fused){
    gemm_up_kernel<4608,384><<<dim3(M/64,18),256,0,stream>>>(y, cw1T, h, cb1);
    gemm_kernel<64,384,4608,E_FINAL><<<dim3(M/64,3),256,0,stream>>>(
        h, cw2T, d_out, cb2s, nullptr, x2);
  } else {
    for (int i = 0; i < 3; ++i){
      gemm_up_kernel<1536,384><<<dim3(M/64,6),256,0,stream>>>(y, cw1T + i*W11, h, cb1 + i*HID);
      if (i < 2)
        gemm_kernel<64,384,1536,E_ACC_F32><<<dim3(M/64,3),256,0,stream>>>(
            h, cw2T + i*W11, nullptr, cb2 + i*DIM, nullptr, x2);
      else
        gemm_kernel<64,384,1536,E_FINAL><<<dim3(M/64,3),256,0,stream>>>(
            h, cw2T + i*W11, d_out, cb2 + i*DIM, nullptr, x2);
    }
  }
}